// Round 3
// baseline (282.888 us; speedup 1.0000x reference)
//
#include <hip/hip_runtime.h>
#include <math.h>

// FNO spectral block: B=4, S=16, C=64, R=128, MODES=16
// bid = n*64+c, n = b*16+s. Mode slot m = kxi*16+ky, kx_eff = kxi<16 ? kxi : 96+kxi.
// K1 uses MFMA (16x16x32 bf16) for both DFT passes; intermediates packed bf16.

#define TWO_PI_OVER_128 0.04908738521234052f

typedef __attribute__((ext_vector_type(8))) short bf16x8;
typedef __attribute__((ext_vector_type(4))) float f32x4;
union FragU { uint4 u; bf16x8 s; };

__device__ __forceinline__ unsigned pk(float a, float b) {
  unsigned ua = __float_as_uint(a), ub = __float_as_uint(b);
  ua = (ua + 0x7FFFu + ((ua >> 16) & 1u)) >> 16;
  ub = (ub + 0x7FFFu + ((ub >> 16) & 1u)) >> 16;
  return ua | (ub << 16);
}
__device__ __forceinline__ float2 upk(unsigned v) {
  return make_float2(__uint_as_float(v << 16), __uint_as_float(v & 0xFFFF0000u));
}
__device__ __forceinline__ unsigned bf1(float a) {
  unsigned ua = __float_as_uint(a);
  return (ua + 0x7FFFu + ((ua >> 16) & 1u)) >> 16;
}

// ---------------- Twiddle tables: Et[32 w][128 y], Gt[64 jr][128 x] (bf16) -----
// Et: w<16: cos(w*y*th) ; w>=16: -sin((w-16)*y*th)
// Gt: jr<32: cos(kx(jr)*x*th) ; jr>=32: sin(kx(jr-32)*x*th); kx(j)= j<16? j : 96+j
__global__ __launch_bounds__(256) void ktab(unsigned* __restrict__ Etu,
                                            unsigned* __restrict__ Gtu) {
  const int tid = threadIdx.x;
  for (int i = 0; i < 8; ++i) {          // Et: 2048 u32
    int t = i * 256 + tid;
    int w = t >> 6, y0 = (t & 63) * 2;
    float v[2];
#pragma unroll
    for (int q = 0; q < 2; ++q) {
      int y = y0 + q;
      if (w < 16) v[q] = cosf((float)((w * y) & 127) * TWO_PI_OVER_128);
      else        v[q] = -sinf((float)(((w - 16) * y) & 127) * TWO_PI_OVER_128);
    }
    Etu[t] = bf1(v[0]) | (bf1(v[1]) << 16);
  }
  for (int i = 0; i < 16; ++i) {         // Gt: 4096 u32
    int t = i * 256 + tid;
    int jr = t >> 6, x0 = (t & 63) * 2;
    int j = (jr & 31);
    int kx = (j < 16) ? j : 96 + j;
    float v[2];
#pragma unroll
    for (int q = 0; q < 2; ++q) {
      int x = x0 + q;
      float a = (float)((kx * x) & 127) * TWO_PI_OVER_128;
      v[q] = (jr < 32) ? cosf(a) : sinf(a);
    }
    Gtu[t] = bf1(v[0]) | (bf1(v[1]) << 16);
  }
}

// ---------------- Weights transpose: w[c][o][kx][ky] -> Wt[m][o][c], wsc folded ---
__global__ __launch_bounds__(256) void ktw(const float* __restrict__ w1r,
                                           const float* __restrict__ w1i,
                                           const float* __restrict__ w2r,
                                           const float* __restrict__ w2i,
                                           unsigned* __restrict__ Wt) {
  __shared__ unsigned tile[64 * 65];
  const int o = blockIdx.x & 63, wsel = blockIdx.x >> 6;
  const float* Wr = wsel ? w2r : w1r;
  const float* Wi = wsel ? w2i : w1i;
  const int tid = threadIdx.x;
  for (int mc = 0; mc < 4; ++mc) {
    if (mc) __syncthreads();
    for (int i = 0; i < 16; ++i) {
      int idx = i * 256 + tid;
      int c = idx >> 6, ml = idx & 63;
      int mh = mc * 64 + ml;
      float wsc = ((mh & 15) ? 2.f : 1.f) / 16384.f;
      size_t off = (size_t)(c * 64 + o) * 256 + mh;
      tile[c * 65 + ml] = pk(Wr[off] * wsc, Wi[off] * wsc);
    }
    __syncthreads();
    for (int i = 0; i < 16; ++i) {
      int idx = i * 256 + tid;
      int ml = idx >> 6, c = idx & 63;
      Wt[(size_t)(wsel * 256 + mc * 64 + ml) * 4096 + o * 64 + c] = tile[c * 65 + ml];
    }
  }
}

// ---------------- Stage 1: residual scatter + partial rfft2 via MFMA ----------
__global__ __launch_bounds__(256) void k1_fwd(const float* __restrict__ ref,
                                              const int* __restrict__ lu,
                                              const unsigned* __restrict__ Etu,
                                              const unsigned* __restrict__ Gtu,
                                              float* __restrict__ out,
                                              unsigned* __restrict__ Xf) {
  __shared__ unsigned short imgL[128 * 128];  // bf16, XOR-swizzled 16B chunks
  __shared__ unsigned short A1t[32 * 128];    // A1^T [w][x] bf16, swizzled
  __shared__ unsigned Xout[512];
  const int bid = blockIdx.x;
  const int n = bid >> 6, c = bid & 63;
  const int b = n >> 4, s = n & 15;
  const int tid = threadIdx.x;
  const int l = tid & 63, w = tid >> 6;

  // Preload E fragments (B-operand: col w'=l&15, k=y block) — all waves
  FragU Ef[2][4];
#pragma unroll
  for (int nt = 0; nt < 2; ++nt)
#pragma unroll
    for (int ks = 0; ks < 4; ++ks)
      Ef[nt][ks].u = *(const uint4*)&Etu[(nt * 16 + (l & 15)) * 64 + ks * 16 + (l >> 4) * 4];
  // Preload G fragments (A-operand: row j', k=x block) — waves 0,1 only
  FragU Gf[2][4];
  if (w < 2) {
#pragma unroll
    for (int mtl = 0; mtl < 2; ++mtl)
#pragma unroll
      for (int ks = 0; ks < 4; ++ks)
        Gf[mtl][ks].u = *(const uint4*)&Gtu[((w + 2 * mtl) * 16 + (l & 15)) * 64 + ks * 16 + (l >> 4) * 4];
  }

  // Stage image -> LDS bf16 (swizzled) + masked residual scatter
  const float4* im4 = (const float4*)(ref + (size_t)bid * 16384);
  const int4* lu4 = (const int4*)lu;
  float* outimg = out + (size_t)(b * 64 + c) * 16384;
  for (int i = 0; i < 16; ++i) {
    const int e4 = i * 256 + tid;        // 0..4095
    float4 v = im4[e4];
    int4 L = lu4[e4];
    const int p = e4 * 4;
    if (L.x == s) outimg[p] = v.x;
    if (L.y == s) outimg[p + 1] = v.y;
    if (L.z == s) outimg[p + 2] = v.z;
    if (L.w == s) outimg[p + 3] = v.w;
    const int x = p >> 7, y0 = p & 127;
    const int chunk = (y0 >> 3) ^ (x & 15);
    uint2 pkd = make_uint2(pk(v.x, v.y), pk(v.z, v.w));
    *(uint2*)&imgL[x * 128 + chunk * 8 + (y0 & 7)] = pkd;
  }
  __syncthreads();

  // Step 1: A1 = img(128x128) * E(128x32); wave w -> M-tiles {2w, 2w+1}
  f32x4 acc1[2][2] = {};
#pragma unroll
  for (int mtl = 0; mtl < 2; ++mtl) {
    const int mt = w * 2 + mtl;
    const int x = mt * 16 + (l & 15);
#pragma unroll
    for (int ks = 0; ks < 4; ++ks) {
      const int chunk = (ks * 4 + (l >> 4)) ^ (x & 15);
      FragU a;
      a.u = *(const uint4*)&imgL[x * 128 + chunk * 8];
#pragma unroll
      for (int nt = 0; nt < 2; ++nt)
        acc1[mtl][nt] = __builtin_amdgcn_mfma_f32_16x16x32_bf16(a.s, Ef[nt][ks].s, acc1[mtl][nt], 0, 0, 0);
    }
  }
  // Write A1^T[w'][x] bf16 to LDS (4 consecutive x per reg-quad)
#pragma unroll
  for (int mtl = 0; mtl < 2; ++mtl) {
    const int x0 = (w * 2 + mtl) * 16 + (l >> 4) * 4;
#pragma unroll
    for (int nt = 0; nt < 2; ++nt) {
      const int wp = nt * 16 + (l & 15);
      const int chunk = (x0 >> 3) ^ (wp & 15);
      uint2 w2 = make_uint2(pk(acc1[mtl][nt][0], acc1[mtl][nt][1]),
                            pk(acc1[mtl][nt][2], acc1[mtl][nt][3]));
      *(uint2*)&A1t[wp * 128 + chunk * 8 + (x0 & 7)] = w2;
    }
  }
  __syncthreads();

  // Step 2: P = G(64x128) * A1(128x32); waves 0,1: M-tiles {w, w+2}
  if (w < 2) {
    f32x4 acc2[2][2] = {};
#pragma unroll
    for (int mtl = 0; mtl < 2; ++mtl)
#pragma unroll
      for (int ks = 0; ks < 4; ++ks) {
#pragma unroll
        for (int nt = 0; nt < 2; ++nt) {
          const int wp = nt * 16 + (l & 15);
          const int chunk = (ks * 4 + (l >> 4)) ^ (wp & 15);
          FragU bfr;
          bfr.u = *(const uint4*)&A1t[wp * 128 + chunk * 8];
          acc2[mtl][nt] = __builtin_amdgcn_mfma_f32_16x16x32_bf16(Gf[mtl][ks].s, bfr.s, acc2[mtl][nt], 0, 0, 0);
        }
      }
    // Combine: Re = Pcos[.,Ar] + Psin[.,Ai]; Im = Pcos[.,Ai] - Psin[.,Ar]
#pragma unroll
    for (int r = 0; r < 4; ++r) {
      const int j = w * 16 + (l >> 4) * 4 + r;   // kxi 0..31
      const int ky = l & 15;
      const float re = acc2[0][0][r] + acc2[1][1][r];
      const float im = acc2[0][1][r] - acc2[1][0][r];
      Xout[j * 16 + ky] = pk(re, im);
    }
  }
  __syncthreads();
  ((uint2*)(Xf + (size_t)bid * 512))[tid] = ((uint2*)Xout)[tid];
}

// ---------------- Transpose Xf[bid][m] -> Xf2[m][bid] -------------------------
__global__ __launch_bounds__(256) void kt(const unsigned* __restrict__ Xf,
                                          unsigned* __restrict__ Xf2) {
  __shared__ unsigned tile[64 * 65];
  const int bm = blockIdx.x & 7, bn = blockIdx.x >> 3;
  const int tid = threadIdx.x;
  for (int i = 0; i < 16; ++i) {
    int idx = i * 256 + tid;
    int r = idx >> 6, cc = idx & 63;
    tile[r * 65 + cc] = Xf[(size_t)(bn * 64 + r) * 512 + bm * 64 + cc];
  }
  __syncthreads();
  for (int i = 0; i < 16; ++i) {
    int idx = i * 256 + tid;
    int r = idx >> 6, cc = idx & 63;
    Xf2[(size_t)(bm * 64 + r) * 4096 + bn * 64 + cc] = tile[cc * 65 + r];
  }
}

// ---------------- Stage 2: per-mode complex channel mix ------------------------
__global__ __launch_bounds__(256) void k2_mix(const unsigned* __restrict__ Xf2,
                                              const unsigned* __restrict__ Wt,
                                              unsigned* __restrict__ Yf) {
  __shared__ float2 Xs[64 * 65];
  __shared__ float2 Ws[64 * 65];
  const int m = blockIdx.x;
  const int tid = threadIdx.x;
  for (int i = 0; i < 16; ++i) {
    int e = i * 256 + tid;
    Xs[(e >> 6) * 65 + (e & 63)] = upk(Xf2[(size_t)m * 4096 + e]);
    Ws[(e >> 6) * 65 + (e & 63)] = upk(Wt[(size_t)m * 4096 + e]);
  }
  __syncthreads();
  const int g = tid >> 4, t = tid & 15;
  float accr[4][4] = {}, acci[4][4] = {};
  for (int cc = 0; cc < 64; ++cc) {
    float2 xv[4], wv[4];
#pragma unroll
    for (int k = 0; k < 4; ++k) xv[k] = Xs[(g + 16 * k) * 65 + cc];
#pragma unroll
    for (int j = 0; j < 4; ++j) wv[j] = Ws[(t + 16 * j) * 65 + cc];
#pragma unroll
    for (int k = 0; k < 4; ++k)
#pragma unroll
      for (int j = 0; j < 4; ++j) {
        accr[k][j] += xv[k].x * wv[j].x - xv[k].y * wv[j].y;
        acci[k][j] += xv[k].x * wv[j].y + xv[k].y * wv[j].x;
      }
  }
  __syncthreads();
  unsigned* Os = (unsigned*)Xs;
#pragma unroll
  for (int k = 0; k < 4; ++k)
#pragma unroll
    for (int j = 0; j < 4; ++j) {
      int bo = k * 64 + t + 16 * j;
      Os[bo * 17 + g] = pk(accr[k][j], acci[k][j]);
    }
  __syncthreads();
  for (int i = 0; i < 16; ++i) {
    int e = i * 256 + tid;
    int bo = e >> 4, ss = e & 15;
    Yf[(size_t)bo * 8192 + m * 16 + ss] = Os[bo * 17 + ss];
  }
}

// ---------------- Stage 3: partial irfft2 + accumulate onto residual -----------
__global__ __launch_bounds__(512) void k3_inv(const unsigned* __restrict__ Yf,
                                              const int* __restrict__ lu,
                                              float* __restrict__ out) {
  __shared__ float2 Ys[16 * 512];   // [s][m ^ s]
  __shared__ float tbuf[16 * 138];
  __shared__ float2 tab[128];
  const int bo = blockIdx.x >> 1, half = blockIdx.x & 1;
  const int tid = threadIdx.x;
  if (tid < 128) {
    float sv, cv;
    sincosf((float)tid * TWO_PI_OVER_128, &sv, &cv);
    tab[tid] = make_float2(cv, sv);
  }
  for (int i = 0; i < 16; ++i) {
    int e = i * 512 + tid;
    int ss = e & 15, mm = e >> 4;
    Ys[ss * 512 + (mm ^ ss)] = upk(Yf[(size_t)bo * 8192 + e]);
  }
  __syncthreads();
  const int ky = tid & 15, xl = (tid >> 4) & 3, sg = tid >> 6;
  const int ss0 = sg, ss1 = sg + 8;
  float* outb = out + (size_t)bo * 16384;

  for (int xb = half * 16; xb < half * 16 + 16; ++xb) {
    {
      const int x = xb * 4 + xl;
      const float2 stp = tab[x];
      float c0 = 1.f, s0 = 0.f;
      float tre0 = 0.f, tim0 = 0.f, tre1 = 0.f, tim1 = 0.f;
#pragma unroll
      for (int kxi = 0; kxi < 32; ++kxi) {
        if (kxi == 16) {
          float2 st = tab[(112 * x) & 127];
          c0 = st.x; s0 = st.y;
        }
        const int mb = kxi * 16 + ky;
        const float2 Y0 = Ys[ss0 * 512 + (mb ^ ss0)];
        const float2 Y1 = Ys[ss1 * 512 + (mb ^ ss1)];
        tre0 = fmaf(Y0.x, c0, fmaf(-Y0.y, s0, tre0));
        tim0 = fmaf(Y0.x, s0, fmaf(Y0.y, c0, tim0));
        tre1 = fmaf(Y1.x, c0, fmaf(-Y1.y, s0, tre1));
        tim1 = fmaf(Y1.x, s0, fmaf(Y1.y, c0, tim1));
        float nc = c0 * stp.x - s0 * stp.y, ns = s0 * stp.x + c0 * stp.y;
        c0 = nc; s0 = ns;
      }
      tbuf[ss0 * 138 + xl * 34 + ky * 2] = tre0;
      tbuf[ss0 * 138 + xl * 34 + ky * 2 + 1] = tim0;
      tbuf[ss1 * 138 + xl * 34 + ky * 2] = tre1;
      tbuf[ss1 * 138 + xl * 34 + ky * 2 + 1] = tim1;
    }
    __syncthreads();
    {
      const int xl2 = tid >> 7, y = tid & 127;
      const int p = (xb * 4 + xl2) * 128 + y;
      const float rres = outb[p];      // residual written by k1
      const int ssel = lu[p];
      const float* tb = tbuf + ssel * 138 + xl2 * 34;
      const float2 stpy = tab[y];
      float acc = 0.f, c0 = 1.f, s0 = 0.f;
#pragma unroll
      for (int k2 = 0; k2 < 16; ++k2) {
        const float tre = tb[k2 * 2], tim = tb[k2 * 2 + 1];
        acc = fmaf(tre, c0, fmaf(-tim, s0, acc));
        float nc = c0 * stpy.x - s0 * stpy.y, ns = s0 * stpy.x + c0 * stpy.y;
        c0 = nc; s0 = ns;
      }
      outb[p] = rres + acc;
    }
    __syncthreads();
  }
}

extern "C" void kernel_launch(void* const* d_in, const int* in_sizes, int n_in,
                              void* d_out, int out_size, void* d_ws, size_t ws_size,
                              hipStream_t stream) {
  const float* ref = (const float*)d_in[0];
  const int* lu = (const int*)d_in[2];
  const float* w1r = (const float*)d_in[3];
  const float* w1i = (const float*)d_in[4];
  const float* w2r = (const float*)d_in[5];
  const float* w2i = (const float*)d_in[6];
  float* out = (float*)d_out;

  unsigned* Xf  = (unsigned*)d_ws;            // [4096][512]
  unsigned* Xf2 = Xf  + (size_t)4096 * 512;   // [512][4096]
  unsigned* Wt  = Xf2 + (size_t)4096 * 512;   // [512][64][64]
  unsigned* Yf  = Wt  + (size_t)4096 * 512;   // [256][512][16]
  unsigned* Etu = Yf  + (size_t)4096 * 512;   // 2048 u32
  unsigned* Gtu = Etu + 2048;                 // 4096 u32

  ktab<<<1, 256, 0, stream>>>(Etu, Gtu);
  ktw<<<128, 256, 0, stream>>>(w1r, w1i, w2r, w2i, Wt);
  k1_fwd<<<4096, 256, 0, stream>>>(ref, lu, Etu, Gtu, out, Xf);
  kt<<<512, 256, 0, stream>>>(Xf, Xf2);
  k2_mix<<<512, 256, 0, stream>>>(Xf2, Wt, Yf);
  k3_inv<<<512, 512, 0, stream>>>(Yf, lu, out);
}